// Round 10
// baseline (254.777 us; speedup 1.0000x reference)
//
#include <hip/hip_runtime.h>
#include <math.h>

// Router: x[8192,4096] fp32; Wg,Wc[64,4096]; scores=|cls*silu(gate)|, softmax,
// top-8 of scores+bias, weights = 1 + scores*extra_scale (gathered).
// Out: weights [8192,8] fp32, then indices [8192,8] written as float values.
//
// v9b: v9 with the scope bug removed (stray bh1). Math/bits identical to
// v5..v8 (3-way bf16 split, 6-product order, same per-acc k-order -> P
// bit-identical -> absmax 0). Two pipeline fixes vs v8:
//  - vmcnt retires IN-ORDER (m135): v8 issued the HBM x-prefetch FIRST, so
//    every MFMA's wait-for-B drained the fresh ~900cy prefetch. Now B loads
//    issue first, x-prefetch LAST (youngest, depth-1) -> B wait = vmcnt(1),
//    prefetch consumed a full MFMA-segment later.
//  - occupancy 4 -> 8 waves/SIMD: 512-thr blocks, 8 waves (2rg x 4wc), wave
//    tile 32x32 (acc=16 VGPR), __launch_bounds__(512,8) caps VGPR at 64.
//    Grid (128,8) = 8192 waves = exactly 32/CU, single pass, no tail.

#define T_DIM 8192
#define D_DIM 4096
#define E_DIM 64
#define N2    128      // 64 gate cols + 64 cls cols
#define KTOP  8
#define MB_ROWS 64     // rows per workgroup (2 row-groups of 32)

// LDS fragment layout strides (ushorts): [bf][rg][p][h2][le][j]
#define LDS_H2S 512
#define LDS_PS  1040   // 1024 + 16 pad -> parts shifted 8 banks
#define LDS_RGS (3 * LDS_PS)
#define LDS_BFS (2 * LDS_RGS)

typedef __attribute__((ext_vector_type(8)))  short bfrag8;   // 8 bf16 (4 VGPRs)
typedef __attribute__((ext_vector_type(16))) float f32x16;   // 32x32 C/D frag
typedef __attribute__((ext_vector_type(4)))  float f4;       // clang vec (nt ok)

__device__ __forceinline__ unsigned short f2bf_rne(float f) {
    unsigned int u = __float_as_uint(f);
    unsigned int r = u + 0x7fffu + ((u >> 16) & 1u);        // round-nearest-even
    return (unsigned short)(r >> 16);
}
__device__ __forceinline__ float bf2f(unsigned short h) {
    return __uint_as_float(((unsigned int)h) << 16);
}
// v = bf2f(h) + bf2f(m) + bf2f(l) + eps, |eps| <= 2^-27 |v|
__device__ __forceinline__ void split3(float v, unsigned short& h,
                                       unsigned short& m, unsigned short& l) {
    h = f2bf_rne(v);
    const float r1 = v - bf2f(h);          // exact in fp32
    m = f2bf_rne(r1);
    const float r2 = r1 - bf2f(m);         // exact in fp32
    l = f2bf_rne(r2);
}

// ---------------- Kernel 0: W -> packed fragment-major bf16 hi/mid/lo ----------
// Wpk element index: ((((k32*4 + n)*3 + p)*2 + h2)*64 + lane)*8 + j
//   holds part-p of W[col = n*32 + (lane&31)][k32*32 + h2*16 + (lane>>5)*8 + j]
// => a wave's B fragment load is 64 lanes x 16B CONTIGUOUS (1 KB). Total 3 MB.
__global__ __launch_bounds__(256)
void router_prep(const float* __restrict__ Wg, const float* __restrict__ Wc,
                 unsigned short* __restrict__ Wpk)
{
    const int t   = blockIdx.x * 256 + threadIdx.x;  // 65536 threads
    const int col = t >> 9;                          // 0..127
    const int ch  = t & 511;                         // 8-float chunk within row
    const int k   = ch << 3;

    const float* src = (col < E_DIM) ? (Wg + (size_t)col * D_DIM)
                                     : (Wc + (size_t)(col - E_DIM) * D_DIM);
    const float4 w0 = ((const float4*)(src + k))[0];
    const float4 w1 = ((const float4*)(src + k))[1];
    const float v[8] = {w0.x, w0.y, w0.z, w0.w, w1.x, w1.y, w1.z, w1.w};

    unsigned short hv[8], mv[8], lv[8];
    #pragma unroll
    for (int j = 0; j < 8; ++j) split3(v[j], hv[j], mv[j], lv[j]);

    const int k32 = k >> 5, h2 = (k >> 4) & 1, lh = (k >> 3) & 1;
    const int n = col >> 5, lane = lh * 32 + (col & 31);
    const size_t base = ((((size_t)k32 * 4 + n) * 3 + 0) * 2 + h2) * 512 + (size_t)lane * 8;
    // p stride = 2*512 = 1024 elements
    *(ushort4*)(Wpk + base)          = make_ushort4(hv[0], hv[1], hv[2], hv[3]);
    *(ushort4*)(Wpk + base + 4)      = make_ushort4(hv[4], hv[5], hv[6], hv[7]);
    *(ushort4*)(Wpk + base + 1024)   = make_ushort4(mv[0], mv[1], mv[2], mv[3]);
    *(ushort4*)(Wpk + base + 1028)   = make_ushort4(mv[4], mv[5], mv[6], mv[7]);
    *(ushort4*)(Wpk + base + 2048)   = make_ushort4(lv[0], lv[1], lv[2], lv[3]);
    *(ushort4*)(Wpk + base + 2052)   = make_ushort4(lv[4], lv[5], lv[6], lv[7]);
}

// ---------------- Kernel 1: 3-way-split MFMA GEMM, partials P[ks][T][128] ------
// Block: 512 thr = 8 waves (rg = wid>>2 row-group, wc = wid&3 col-quarter).
// Wave tile 32 rows x 32 cols: 6 B loads + 6 ds_reads + 12 MFMA per k32-step.
// Staging: 512 threads each load ONE f4 of x (nt), split3 once, ds_write
// fragment layout (identical LDS bits to v8 -> P bit-identical).
__global__ __launch_bounds__(512, 8)
void router_gemm(const float* __restrict__ x,
                 const unsigned short* __restrict__ Wpk,
                 float* __restrict__ P,
                 int sliceK)
{
    __shared__ unsigned short sF[2 * LDS_BFS];       // ~25 KB

    const int tid  = threadIdx.x;
    const int lane = tid & 63;
    const int wid  = tid >> 6;
    const int rg   = wid >> 2;           // row-group (0/1)
    const int wc   = wid & 3;            // col-quarter (B n-tile)
    const int l31  = lane & 31;
    const int lh   = lane >> 5;
    const int mb   = blockIdx.x;
    const int ks   = blockIdx.y;
    const int k0   = ks * sliceK;
    const int NT   = sliceK >> 5;        // 32-k steps
    const int brow0 = mb * MB_ROWS;

    // staging map: thread -> (srow 0..63, kq 0..7); one f4 per tile
    const int srow = tid >> 3;
    const int kq   = tid & 7;
    const int rgs  = srow >> 5;          // staging row-group
    const int h2w  = kq >> 2;
    const int lew  = ((kq >> 1) & 1) * 32 + (srow & 31);
    const int jw   = (kq & 1) * 4;
    const int wbase = rgs * LDS_RGS + h2w * LDS_H2S + lew * 8 + jw;
    const float* gsrc = x + (size_t)(brow0 + srow) * D_DIM + k0 + kq * 4;

    f32x16 acc;
    #pragma unroll
    for (int r = 0; r < 16; ++r) acc[r] = 0.f;

    // split one f4 into LDS at buffer bf_ (same values/addresses as v8)
    #define WRITE_ONE(v_, bf_)                                                   \
        {                                                                        \
            ushort4 hv_, mv_, lv_;                                               \
            unsigned short h_, m_, l_;                                           \
            split3((v_).x, h_, m_, l_); hv_.x = h_; mv_.x = m_; lv_.x = l_;      \
            split3((v_).y, h_, m_, l_); hv_.y = h_; mv_.y = m_; lv_.y = l_;      \
            split3((v_).z, h_, m_, l_); hv_.z = h_; mv_.z = m_; lv_.z = l_;      \
            split3((v_).w, h_, m_, l_); hv_.w = h_; mv_.w = m_; lv_.w = l_;      \
            const int o_ = (bf_) * LDS_BFS + wbase;                              \
            *(ushort4*)&sF[o_]              = hv_;                               \
            *(ushort4*)&sF[o_ + LDS_PS]     = mv_;                               \
            *(ushort4*)&sF[o_ + 2 * LDS_PS] = lv_;                               \
        }

    // prologue: stage tile 0
    {
        const f4 v0 = __builtin_nontemporal_load((const f4*)gsrc);
        WRITE_ONE(v0, 0);
    }
    asm volatile("s_waitcnt lgkmcnt(0)" ::: "memory");
    __builtin_amdgcn_s_barrier();

    for (int t = 0; t < NT; ++t) {
        const int bf = t & 1;
        const int fbase = bf * LDS_BFS + rg * LDS_RGS;
        const size_t k32 = (size_t)((k0 + t * 32) >> 5);
        const bool more = (t + 1 < NT);

        // ---- B loads FIRST (L2-hot); x prefetch issued LAST (youngest) so the
        //      MFMA wait-for-B (vmcnt(1)) never drains the HBM prefetch (m135).
        const unsigned short* bb0 =
            Wpk + ((((k32 * 4 + wc) * 3 + 0) * 2 + 0) * 64 + lane) * 8;
        const bfrag8 bh0 = *(const bfrag8*)(bb0);
        const bfrag8 bm0 = *(const bfrag8*)(bb0 + 1024);
        const bfrag8 bl0 = *(const bfrag8*)(bb0 + 2048);
        const unsigned short* bb1 = bb0 + 512;              // h2=1 (stride 512)
        const bfrag8 BH1 = *(const bfrag8*)(bb1);
        const bfrag8 BM1 = *(const bfrag8*)(bb1 + 1024);
        const bfrag8 BL1 = *(const bfrag8*)(bb1 + 2048);

        f4 xa;
        if (more) xa = __builtin_nontemporal_load((const f4*)(gsrc + (t + 1) * 32));

        // ---- A fragments (linear conflict-free ds_read_b128) + MFMAs
        {
            const int ab0 = fbase + 0 * LDS_H2S + lane * 8;
            const bfrag8 ah = *(const bfrag8*)&sF[ab0];
            const bfrag8 am = *(const bfrag8*)&sF[ab0 + LDS_PS];
            const bfrag8 al = *(const bfrag8*)&sF[ab0 + 2 * LDS_PS];
            // smallest products first (same per-acc order as v3..v8)
            acc = __builtin_amdgcn_mfma_f32_32x32x16_bf16(ah, bl0, acc, 0, 0, 0);
            acc = __builtin_amdgcn_mfma_f32_32x32x16_bf16(al, bh0, acc, 0, 0, 0);
            acc = __builtin_amdgcn_mfma_f32_32x32x16_bf16(am, bm0, acc, 0, 0, 0);
            acc = __builtin_amdgcn_mfma_f32_32x32x16_bf16(ah, bm0, acc, 0, 0, 0);
            acc = __builtin_amdgcn_mfma_f32_32x32x16_bf16(am, bh0, acc, 0, 0, 0);
            acc = __builtin_amdgcn_mfma_f32_32x32x16_bf16(ah, bh0, acc, 0, 0, 0);
        }
        {
            const int ab1 = fbase + 1 * LDS_H2S + lane * 8;
            const bfrag8 ah = *(const bfrag8*)&sF[ab1];
            const bfrag8 am = *(const bfrag8*)&sF[ab1 + LDS_PS];
            const bfrag8 al = *(const bfrag8*)&sF[ab1 + 2 * LDS_PS];
            acc = __builtin_amdgcn_mfma_f32_32x32x16_bf16(ah, BL1, acc, 0, 0, 0);
            acc = __builtin_amdgcn_mfma_f32_32x32x16_bf16(al, BH1, acc, 0, 0, 0);
            acc = __builtin_amdgcn_mfma_f32_32x32x16_bf16(am, BM1, acc, 0, 0, 0);
            acc = __builtin_amdgcn_mfma_f32_32x32x16_bf16(ah, BM1, acc, 0, 0, 0);
            acc = __builtin_amdgcn_mfma_f32_32x32x16_bf16(am, BH1, acc, 0, 0, 0);
            acc = __builtin_amdgcn_mfma_f32_32x32x16_bf16(ah, BH1, acc, 0, 0, 0);
        }

        // ---- write tile t+1 (waits vmcnt(0) for xa -- covered by MFMA segment)
        if (more) WRITE_ONE(xa, bf ^ 1);
        asm volatile("s_waitcnt lgkmcnt(0)" ::: "memory");
        __builtin_amdgcn_s_barrier();
    }
    #undef WRITE_ONE

    // store partial C tile: P[ks][row][col], non-temporal (read once by topk)
    // C/D (m74/m101): col = lane&31, row = (r&3) + 8*(r>>2) + 4*(lane>>5)
    float* Pb = P + ((size_t)ks * T_DIM + brow0 + rg * 32) * N2 + wc * 32 + l31;
    #pragma unroll
    for (int r = 0; r < 16; ++r) {
        const int wrow = (r & 3) + 8 * (r >> 2) + 4 * lh;
        __builtin_nontemporal_store(acc[r], &Pb[(size_t)wrow * N2]);
    }
}

// ---------------- Kernel 2: reduce slices + silu/abs/softmax + biased top-8 ----
// (unchanged from the passing kernel — exact index ordering proven)
__global__ __launch_bounds__(256)
void router_topk(const float* __restrict__ P,
                 const float* __restrict__ scale,
                 const float* __restrict__ bias,
                 float* __restrict__ out,
                 int ksplit)
{
    const int lane = threadIdx.x & 63;   // expert id
    const int wid  = threadIdx.x >> 6;
    const int row  = blockIdx.x * 4 + wid;

    float g = 0.f, c = 0.f;
    for (int ks = 0; ks < ksplit; ++ks) {
        const float* p = P + ((size_t)ks * T_DIM + row) * N2;
        g += p[lane];
        c += p[E_DIM + lane];
    }
    const float sg = g / (1.f + expf(-g));   // silu(gate)
    const float v  = fabsf(c * sg);          // score pre-softmax

    // fp32 softmax across the 64 lanes
    float m = v;
    #pragma unroll
    for (int off = 32; off >= 1; off >>= 1) m = fmaxf(m, __shfl_xor(m, off));
    const float e = expf(v - m);
    float Z = e;
    #pragma unroll
    for (int off = 32; off >= 1; off >>= 1) Z += __shfl_xor(Z, off);
    const float s = e / Z;

    const float sc  = scale[lane];
    float cur = s + bias[lane];              // selection key

    float myw = 0.f; int myi = 0;
    #pragma unroll
    for (int j = 0; j < KTOP; ++j) {
        // wave argmax, ties -> lowest index (matches jax.lax.top_k)
        float bv = cur; int bi = lane;
        #pragma unroll
        for (int off = 32; off >= 1; off >>= 1) {
            const float ov = __shfl_xor(bv, off);
            const int   oi = __shfl_xor(bi, off);
            if (ov > bv || (ov == bv && oi < bi)) { bv = ov; bi = oi; }
        }
        const float s_bi  = __shfl(s,  bi);
        const float sc_bi = __shfl(sc, bi);
        const float w = 1.f + s_bi * sc_bi;  // "original" gathered at bi
        if (lane == j)  { myw = w; myi = bi; }
        if (lane == bi) cur = -INFINITY;
    }

    if (lane < KTOP) {
        out[(size_t)row * KTOP + lane] = myw;
        out[(size_t)T_DIM * KTOP + (size_t)row * KTOP + lane] = (float)myi;
    }
}

extern "C" void kernel_launch(void* const* d_in, const int* in_sizes, int n_in,
                              void* d_out, int out_size, void* d_ws, size_t ws_size,
                              hipStream_t stream)
{
    const float* x  = (const float*)d_in[0];
    const float* Wg = (const float*)d_in[1];
    const float* Wc = (const float*)d_in[2];
    const float* sc = (const float*)d_in[3];
    const float* bs = (const float*)d_in[4];
    float* out = (float*)d_out;
    float* P   = (float*)d_ws;

    const size_t PER = (size_t)T_DIM * N2 * sizeof(float);           // 4 MB per slice
    const size_t WSP = (size_t)N2 * D_DIM * sizeof(unsigned short);  // 1 MB per W part

    // Need S*4MB (partials) + 3MB (packed W); degrade gracefully if ws is small.
    int S = 8;
    while (S > 1 && (size_t)S * PER + 3 * WSP > ws_size) S >>= 1;
    const int sliceK = D_DIM / S;

    unsigned short* Wpk = (unsigned short*)((char*)d_ws + (size_t)S * PER);

    router_prep<<<256, 256, 0, stream>>>(Wg, Wc, Wpk);
    router_gemm<<<dim3(T_DIM / MB_ROWS, S), 512, 0, stream>>>(x, Wpk, P, sliceK);
    router_topk<<<T_DIM / 4, 256, 0, stream>>>(P, sc, bs, out, S);
}